// Round 20
// baseline (81.506 us; speedup 1.0000x reference)
//
#include <hip/hip_runtime.h>
#include <hip/hip_bf16.h>

#define NE     64
#define HDIM   4096
#define NTOK   16384
#define TOKB   32                // tokens per block; 4 waves split K
#define KPH    128               // k staged per phase (512B/row)
#define NPH    (HDIM / KPH)      // 32 phases
#define NCHUNK (HDIM / 32)       // 128 global 32-k chunks
#define PT     33                // LDS k-row stride pad (floats)
#define RST    65                // reduction token stride (floats)

typedef __attribute__((ext_vector_type(8))) short bf16x8;   // 8 bf16 = 4 VGPR
typedef __attribute__((ext_vector_type(4))) float f32x4;    // MFMA acc

union FragU { uint4 u; bf16x8 v; };

// round-to-nearest-even f32 -> bf16 (bits), no NaN handling (inputs finite)
__device__ __forceinline__ unsigned rne_bf16(float f) {
    unsigned v = __float_as_uint(f);
    return (v + 0x7FFFu + ((v >> 16) & 1u)) >> 16;
}

// split 8 fp32 -> hi (truncate) + lo (rne of residual); numerics identical R4-R19
__device__ __forceinline__ void split8f(const float* s, FragU& hi, FragU& lo) {
#pragma unroll
    for (int w = 0; w < 4; ++w) {
        const unsigned u0 = __float_as_uint(s[2 * w]);
        const unsigned u1 = __float_as_uint(s[2 * w + 1]);
        const unsigned h0 = u0 & 0xFFFF0000u, h1 = u1 & 0xFFFF0000u;
        ((unsigned*)&hi.u)[w] = (h0 >> 16) | h1;
        const float l0 = __uint_as_float(u0) - __uint_as_float(h0);
        const float l1 = __uint_as_float(u1) - __uint_as_float(h1);
        ((unsigned*)&lo.u)[w] = rne_bf16(l0) | (rne_bf16(l1) << 16);
    }
}

// ---------------------------------------------------------------------------
// Pack W [64][4096] fp32 into MFMA B-fragment order, split hi/lo bf16.
// elem j of lane l at [(chunk*4+etile)*64+l] = W[etile*16+(l&15)][chunk*32+(l>>4)*8+j]
// ---------------------------------------------------------------------------
__global__ __launch_bounds__(256) void prep_w(
    const float* __restrict__ W, uint4* __restrict__ wfh, uint4* __restrict__ wfl) {
    const int idx = blockIdx.x * 256 + threadIdx.x;   // 32768 = 128*4*64
    const int l  = idx & 63;
    const int ce = idx >> 6;
    const int e  = ce & 3;
    const int c  = ce >> 2;
    const float* src = W + (size_t)(e * 16 + (l & 15)) * HDIM + c * 32 + (l >> 4) * 8;

    unsigned hw[4], lw[4];
#pragma unroll
    for (int w = 0; w < 4; ++w) {
        const float x0 = src[2 * w], x1 = src[2 * w + 1];
        const unsigned u0 = __float_as_uint(x0), u1 = __float_as_uint(x1);
        const unsigned h0 = u0 & 0xFFFF0000u, h1 = u1 & 0xFFFF0000u;
        hw[w] = (h0 >> 16) | h1;
        const float l0 = x0 - __uint_as_float(h0);
        const float l1 = x1 - __uint_as_float(h1);
        lw[w] = rne_bf16(l0) | (rne_bf16(l1) << 16);
    }
    wfh[idx] = make_uint4(hw[0], hw[1], hw[2], hw[3]);
    wfl[idx] = make_uint4(lw[0], lw[1], lw[2], lw[3]);
}

#define MFMA_STEP(AH0, AL0, AH1, AL1, WH, WL)                                          \
    _Pragma("unroll")                                                                   \
    for (int e = 0; e < 4; ++e) {                                                       \
        acc[0][e] = __builtin_amdgcn_mfma_f32_16x16x32_bf16(AH0.v, WH[e].v, acc[0][e], 0, 0, 0); \
        acc[0][e] = __builtin_amdgcn_mfma_f32_16x16x32_bf16(AL0.v, WH[e].v, acc[0][e], 0, 0, 0); \
        acc[0][e] = __builtin_amdgcn_mfma_f32_16x16x32_bf16(AH0.v, WL[e].v, acc[0][e], 0, 0, 0); \
        acc[1][e] = __builtin_amdgcn_mfma_f32_16x16x32_bf16(AH1.v, WH[e].v, acc[1][e], 0, 0, 0); \
        acc[1][e] = __builtin_amdgcn_mfma_f32_16x16x32_bf16(AL1.v, WH[e].v, acc[1][e], 0, 0, 0); \
        acc[1][e] = __builtin_amdgcn_mfma_f32_16x16x32_bf16(AH1.v, WL[e].v, acc[1][e], 0, 0, 0); \
    }

// ---------------------------------------------------------------------------
// GEMM via split-bf16 MFMA — NO GLOBAL PARTIALS. Block = 32 tokens x full
// HDIM; the 4 waves split K (wave w takes chunk 4T+w of phase T); final
// cross-wave sum via one LDS pass (reusing the staging buffer); block
// writes FINAL logits. Saves the entire partial round-trip (R19 proved
// traffic is the limiter and 8 waves/CU suffice). Each phase stages
// 32 rows x 512B contiguous (vs 128B) — better DRAM page locality.
// Bank patterns: stage (4kq+i+trow)%32 <=2-way; read (8u+j+t)%32 <=2-way;
// reduce pad-65 <=2-way. R11/R19 barrier skeleton throughout.
// ---------------------------------------------------------------------------
__global__ __launch_bounds__(256) void gemm_logits_mfma(
    const float* __restrict__ x, const uint4* __restrict__ wfh,
    const uint4* __restrict__ wfl, float* __restrict__ logits) {
    __shared__ float xs[2][KPH][PT];   // 33,792 B; reused for reduction

    const int tid  = threadIdx.x;
    const int lane = tid & 63;
    const int wv   = tid >> 6;            // wave 0..3 (K-quarter owner)
    const int t0   = blockIdx.x * TOKB;
    const int r    = lane & 15;           // A token row in frag / B expert row
    const int u    = lane >> 4;           // 0..3 k-quad
    const int wk   = wv * 32;             // wave's k-slice within staged phase

    f32x4 acc[2][4];
#pragma unroll
    for (int f = 0; f < 2; ++f)
#pragma unroll
        for (int e = 0; e < 4; ++e) acc[f][e] = (f32x4){0.f, 0.f, 0.f, 0.f};

    // staging: 8 consecutive tids cover one row's 512B phase-chunk (4 float4)
    const int trow = tid >> 3;            // 0..31
    const int kq   = tid & 7;
    const float* gsrc = x + (size_t)(t0 + trow) * HDIM + kq * 4;

    const uint4* whb = wfh + lane;
    const uint4* wlb = wfl + lane;

    float4 ldE[4], ldO[4];
    FragU WhA[4], WlA[4], WhB[4], WlB[4];

#define LOADT(LD, T)                                                              \
    _Pragma("unroll")                                                             \
    for (int p = 0; p < 4; ++p)                                                   \
        LD[p] = *reinterpret_cast<const float4*>(gsrc + (T) * KPH + p * 32);

#define WRITET(B, LD)                                                             \
    _Pragma("unroll")                                                             \
    for (int p = 0; p < 4; ++p) {                                                 \
        xs[B][kq * 4 + p * 32 + 0][trow] = LD[p].x;                               \
        xs[B][kq * 4 + p * 32 + 1][trow] = LD[p].y;                               \
        xs[B][kq * 4 + p * 32 + 2][trow] = LD[p].z;                               \
        xs[B][kq * 4 + p * 32 + 3][trow] = LD[p].w;                               \
    }

#define LOADW(WH, WL_, CC)                                                        \
    {                                                                             \
        const size_t c_ = (size_t)(CC) * 256;                                     \
        _Pragma("unroll")                                                         \
        for (int e = 0; e < 4; ++e) {                                             \
            WH[e].u = whb[c_ + e * 64];                                           \
            WL_[e].u = wlb[c_ + e * 64];                                          \
        }                                                                         \
    }

#define COMPUTE(B, WH, WL_)                                                       \
    {                                                                             \
        float a0[8], a1[8];                                                       \
        const float* xb = &xs[B][wk + u * 8][0] + r;                              \
        _Pragma("unroll")                                                         \
        for (int j = 0; j < 8; ++j) { a0[j] = xb[j * PT]; a1[j] = xb[j * PT + 16]; } \
        FragU ah0, al0, ah1, al1;                                                 \
        split8f(a0, ah0, al0);                                                    \
        split8f(a1, ah1, al1);                                                    \
        MFMA_STEP(ah0, al0, ah1, al1, WH, WL_)                                    \
    }

    // Prologue: W(chunk wv)->A; phases 0,1,2 in flight; phase 0 in buf0.
    LOADW(WhA, WlA, wv)
    LOADT(ldE, 0)
    LOADT(ldO, 1)
    WRITET(0, ldE)
    LOADT(ldE, 2)
    __syncthreads();

    for (int t2 = 0; t2 < NPH; t2 += 2) {
        // ===== even phase t2: buf0, W set A; ldO holds phase t2+1 =====
        {
            LOADW(WhB, WlB, 4 * (t2 + 1) + wv)
            COMPUTE(0, WhA, WlA)
            WRITET(1, ldO)
            if (t2 + 3 < NPH) { LOADT(ldO, t2 + 3) }
            __syncthreads();
        }
        // ===== odd phase t2+1: buf1, W set B; ldE holds phase t2+2 =====
        {
            const int tn = t2 + 2;
            if (tn < NPH) { LOADW(WhA, WlA, 4 * tn + wv) }
            COMPUTE(1, WhB, WlB)
            if (tn < NPH) {
                WRITET(0, ldE)
                if (t2 + 4 < NPH) { LOADT(ldE, t2 + 4) }
                __syncthreads();
            }
        }
    }

    // Cross-wave K-reduction in LDS (reuse xs), then write FINAL logits.
    // red[w][tok][exp] with token stride 65 (bank-safe). Sum order w0..w3
    // is fixed -> deterministic.
    float* red = &xs[0][0][0];
    __syncthreads();   // all waves done reading xs
#pragma unroll
    for (int f = 0; f < 2; ++f)
#pragma unroll
        for (int e = 0; e < 4; ++e)
#pragma unroll
            for (int rr = 0; rr < 4; ++rr)
                red[wv * (TOKB * RST) + (f * 16 + u * 4 + rr) * RST + e * 16 + r] =
                    acc[f][e][rr];
    __syncthreads();

    const int stok = tid >> 3;            // 0..31
    const int se0  = (tid & 7) * 8;       // 8 experts per thread
    float sum[8];
#pragma unroll
    for (int i = 0; i < 8; ++i) {
        float s = red[stok * RST + se0 + i];
#pragma unroll
        for (int w = 1; w < 4; ++w)
            s += red[w * (TOKB * RST) + stok * RST + se0 + i];
        sum[i] = s;
    }
    float* lrow = logits + (size_t)(t0 + stok) * NE + se0;
    *reinterpret_cast<float4*>(lrow)     = make_float4(sum[0], sum[1], sum[2], sum[3]);
    *reinterpret_cast<float4*>(lrow + 4) = make_float4(sum[4], sum[5], sum[6], sum[7]);
#undef LOADT
#undef WRITET
#undef LOADW
#undef COMPUTE
}

// ---------------------------------------------------------------------------
// Router: WAVE-PER-TOKEN, lane = expert (R11, proven). Logits are already
// final in out — just read, softmax*mask -> scores, top-2 via packed
// 64-bit key max-reduce (tie -> lowest index, matching jax.lax.top_k).
// Out layout: [scores 16384*64][logits 16384*64][weights 16384*2][indices 16384*2]
// ---------------------------------------------------------------------------
__global__ __launch_bounds__(256) void router_kernel(
    const float* __restrict__ mask, float* __restrict__ out) {
    const int lane = threadIdx.x & 63;
    const int wv   = threadIdx.x >> 6;
    const int t    = blockIdx.x * 4 + wv;

    const float l = out[(size_t)NTOK * NE + (size_t)t * NE + lane];

    // softmax over 64 lanes
    float mx = l;
#pragma unroll
    for (int m = 32; m; m >>= 1) mx = fmaxf(mx, __shfl_xor(mx, m, 64));
    const float ev = __expf(l - mx);
    float s = ev;
#pragma unroll
    for (int m = 32; m; m >>= 1) s += __shfl_xor(s, m, 64);
    const float sc = mask[(size_t)(t >> 12) * NE + lane] * (ev / s);
    out[(size_t)t * NE + lane] = sc;

    // top-2 via packed key max-reduce
    const unsigned long long key =
        ((unsigned long long)__float_as_uint(sc) << 6) | (unsigned long long)(63 - lane);
    unsigned long long k1 = key;
#pragma unroll
    for (int m = 32; m; m >>= 1) {
        const unsigned long long o = __shfl_xor(k1, m, 64);
        if (o > k1) k1 = o;
    }
    const int   i1 = 63 - (int)(k1 & 63ull);
    const float v1 = __uint_as_float((unsigned)(k1 >> 6));

    unsigned long long k2 = (lane == i1) ? 0ull : key;
#pragma unroll
    for (int m = 32; m; m >>= 1) {
        const unsigned long long o = __shfl_xor(k2, m, 64);
        if (o > k2) k2 = o;
    }
    const int   i2 = 63 - (int)(k2 & 63ull);
    const float v2 = __uint_as_float((unsigned)(k2 >> 6));

    if (lane == 0) {
        const float e2v = __expf(v2 - v1);   // v1 >= v2
        float w1 = 1.f / (1.f + e2v);
        float w2 = e2v / (1.f + e2v);
        const float sw = w1 + w2;            // L1 renorm (kept for parity)
        w1 /= sw; w2 /= sw;
        const size_t wo = (size_t)2 * NTOK * NE;
        out[wo + (size_t)t * 2 + 0] = w1;
        out[wo + (size_t)t * 2 + 1] = w2;
        const size_t io = wo + (size_t)NTOK * 2;
        out[io + (size_t)t * 2 + 0] = (float)i1;
        out[io + (size_t)t * 2 + 1] = (float)i2;
    }
}

extern "C" void kernel_launch(void* const* d_in, const int* in_sizes, int n_in,
                              void* d_out, int out_size, void* d_ws, size_t ws_size,
                              hipStream_t stream) {
    const float* x    = (const float*)d_in[0];
    const float* mask = (const float*)d_in[1];
    const float* W    = (const float*)d_in[2];
    float* out = (float*)d_out;

    // ws layout: wfh (512 KB) + wfl (512 KB) — no partials needed
    uint4* wfh = (uint4*)d_ws;
    uint4* wfl = wfh + (size_t)NCHUNK * 4 * 64;
    float* logits = out + (size_t)NTOK * NE;

    prep_w<<<dim3(NCHUNK * 4 * 64 / 256), dim3(256), 0, stream>>>(W, wfh, wfl);
    gemm_logits_mfma<<<dim3(NTOK / TOKB), dim3(256), 0, stream>>>(
        x, wfh, wfl, logits);
    router_kernel<<<dim3(NTOK / 4), dim3(256), 0, stream>>>(mask, out);
}